// Round 15
// baseline (106.429 us; speedup 1.0000x reference)
//
#include <hip/hip_runtime.h>
#include <hip/hip_bf16.h>

// LoRA-factored 3x3 conv. out fp32. Input dtypes runtime-detected.
// x: [16,128,56,56], A: [256,16], B: [16,1152] -> out: [16,256,56,56]
// R19: two-kernel split. R15-R18 proved the fused kernel's ~31us is its
// phase-convoy (MFMA count null R17, max-TLP null R18): the 51MB write
// burst sits at the tail of every block's serial chain. Cut at the LoRA
// bottleneck tmp[16,16,3136] (3.2MB):
//  K1 = R17 verified staging/MFMA/kh-reduce, writes tmp (7KB/block) —
//      write-burst phase gone. + XCD swizzle: XCD k owns batches {2k,2k+1},
//      consecutive same-XCD blocks = consecutive hb -> x L2-resident.
//  K2 = pure streaming expand out = A.tmp: 896 x 448thr, exact l-tiling,
//      16 coalesced tmp loads (L3) + 32 o x 16 SGPR-FMA + nt-stores.
//      No LDS/barriers -> writes at ~fillBuffer rate.
// Verified carried: swizzled [px][c] LDS (slot^(px&7), 256B pitch), batched
// b128 staging, b128 read addressing, Bfrag hi/lo frag order + skip-lo when
// B bf16 (R17), C layout col=lane&15,row=(lane>>4)*4+reg, detect (R3).

#define Bn 16
#define Cc 128
#define Hh 56
#define Ww 56
#define Ll (Hh * Ww)      // 3136
#define Rr 16
#define Oo 256
#define KF (Cc * 9)       // 1152
#define NKS 36            // K-steps: 1152/32
#define W2 58             // padded px range
#define RPITCH 128        // u16 per pixel in LDS (=256B, no pad)
#define ROWB (W2 * RPITCH) // 7424 u16 per staged row
#define HB 2              // output rows per block

typedef __attribute__((ext_vector_type(8))) short bfrag_t;  // 8 bf16 (16B)
typedef __attribute__((ext_vector_type(4))) float f32x4;    // C frag

__device__ __forceinline__ float bf16_bits(unsigned short u) {
    return __uint_as_float(((unsigned)u) << 16);
}

__device__ __forceinline__ unsigned short bf16_rne(float f) {
    const unsigned u = __float_as_uint(f);
    const unsigned r = u + 0x7FFFu + ((u >> 16) & 1u);
    return (unsigned short)(r >> 16);
}

// bf16-packed detect (proven R3).
__device__ __forceinline__ bool detect_bf16(const void* __restrict__ p) {
    const unsigned* w = (const unsigned*)p;
    int c = 0;
#pragma unroll
    for (int i = 0; i < 32; ++i) {
        const unsigned e = (w[i] >> 7) & 0xFFu;
        c += (e >= 96u && e <= 144u) ? 1 : 0;
    }
    return c >= 20;
}

// ---- prep: Bfrag[kstep][hi/lo][lane][8e] bf16 (frag order, tap-major K),
//      Afp[o][r] fp32. (Unchanged R11-R18 - harness-verified.)
__global__ __launch_bounds__(256) void prep_frag(
    const void* __restrict__ A, const void* __restrict__ Bm,
    unsigned short* __restrict__ Bfrag, float* __restrict__ Afp)
{
    const bool ab = detect_bf16(A);
    const bool bb = detect_bf16(Bm);
    const int i = blockIdx.x * 256 + threadIdx.x;
    if (i < NKS * 512) {
        const int kstep = i >> 9, rem = i & 511;
        const int l = rem >> 3, e = rem & 7;
        const int r = l & 15, g = l >> 4;
        const int kp = kstep * 32 + g * 8 + e;   // tap-major k'
        const int tap = kp >> 7, c = kp & 127;
        const int k = c * 9 + tap;               // torch Unfold order (c,kh,kw)
        const float v = bb ? bf16_bits(((const unsigned short*)Bm)[r * KF + k])
                           : ((const float*)Bm)[r * KF + k];
        const unsigned short hi = bf16_rne(v);
        const float lov = v - bf16_bits(hi);
        Bfrag[(kstep * 2 + 0) * 512 + rem] = hi;
        Bfrag[(kstep * 2 + 1) * 512 + rem] = bf16_rne(lov);
    }
    if (i < Oo * Rr) {
        Afp[i] = ab ? bf16_bits(((const unsigned short*)A)[i])
                    : ((const float*)A)[i];
    }
}

#define MFB(A, B, C) __builtin_amdgcn_mfma_f32_16x16x32_bf16((A), (B), (C), 0, 0, 0)

// ---- K1: conv -> tmp[b][r][l]. One block = (b, rows h0,h0+1).
//      8 waves = 4 px-tiles x 2 K-halves. BB: skip zero lo-correction.
template<bool XB, bool BB>
__device__ __forceinline__ void k1_body(
    const void* __restrict__ x,
    const unsigned short* __restrict__ Bfrag,
    float* __restrict__ tmpo,
    unsigned short* __restrict__ xs)      // [4*ROWB] u16, 59392 B
{
    const int tid  = threadIdx.x;
    const int lane = tid & 63;
    const int wv   = __builtin_amdgcn_readfirstlane(tid >> 6);  // wave 0..7
    const int t    = wv & 3;              // px-tile 0..3
    const int kh   = wv >> 2;             // K-half 0..1 (cb pair)

    // XCD swizzle: XCD k = lin&7 owns batches {2k, 2k+1}, consecutive j ->
    // consecutive hb -> x rows L2-resident per XCD.
    const int lin  = blockIdx.x;          // 0..447
    const int xcd  = lin & 7;
    const int j    = lin >> 3;            // 0..55
    const int boff = (j >= 28) ? 1 : 0;
    const int hb   = j - 28 * boff;
    const int b    = xcd * 2 + boff;
    const int h0   = hb * HB;

    // ---- stage 4 x-rows (h0-1 .. h0+2) into swizzled LDS [px][c]. (R15/R17)
    {
        const int l   = lane;
        const bool lok = (l < Ww);
#pragma unroll
        for (int rr = 0; rr < HB + 2; ++rr) {
            const int hh = h0 - 1 + rr;
            unsigned short* xr = xs + rr * ROWB;
            if (hh >= 0 && hh < Hh) {
                if (lok) {
                    const unsigned gb = (unsigned)(b * Cc * Ll + hh * Ww + l);
#pragma unroll
                    for (int it = 0; it < 2; ++it) {
                        const int cs_ = it * 8 + wv;     // cslot 0..15
                        const int c0  = cs_ * 8;
                        bfrag_t v;
#pragma unroll
                        for (int jj = 0; jj < 8; ++jj) {
                            if constexpr (XB) {
                                v[jj] = (short)((const unsigned short*)x)[
                                    gb + (unsigned)((c0 + jj) * Ll)];
                            } else {
                                v[jj] = (short)bf16_rne(((const float*)x)[
                                    gb + (unsigned)((c0 + jj) * Ll)]);
                            }
                        }
                        const int sp = cs_ ^ ((l + 1) & 7);
                        *(bfrag_t*)((char*)xr + (l + 1) * 256 + sp * 16) = v;
                    }
                }
            } else {
                unsigned* xw = (unsigned*)xr;
#pragma unroll
                for (int it = 0; it < 7; ++it) xw[it * 512 + tid] = 0u;
                if (tid < 3712 - 7 * 512) xw[7 * 512 + tid] = 0u;
            }
        }
        if (tid < 128) {
#pragma unroll
            for (int rr = 0; rr < HB + 2; ++rr) {
                xs[rr * ROWB + tid] = 0;
                xs[rr * ROWB + 57 * RPITCH + tid] = 0;
            }
        }
    }
    __syncthreads();

    // ---- MFMA over this wave's K-half (cb in {2kh, 2kh+1}). (R17)
    const int col = lane & 15;
    const int g   = lane >> 4;
    const int px  = t * 16 + col;
    const int pxc = px < Ww ? px : Ww - 1;

    unsigned off6[6];
#pragma unroll
    for (int dwv = 0; dwv < 3; ++dwv)
#pragma unroll
        for (int cbi = 0; cbi < 2; ++cbi) {
            const int cb = kh * 2 + cbi;
            const int p2 = pxc + dwv;
            off6[dwv * 2 + cbi] = (unsigned)(p2 * 256 +
                (((cb * 4 + g) ^ (p2 & 7)) << 4));
        }

    f32x4 acc0 = {0.f, 0.f, 0.f, 0.f};
    f32x4 acc1 = {0.f, 0.f, 0.f, 0.f};
    const bfrag_t* __restrict__ bfp = (const bfrag_t*)Bfrag;

#pragma unroll
    for (int tap = 0; tap < 9; ++tap) {
        const int dh = tap / 3, dw = tap - dh * 3;
#pragma unroll
        for (int cbi = 0; cbi < 2; ++cbi) {
            const int cb = kh * 2 + cbi;
            const int ks = tap * 4 + cb;
            const bfrag_t ahi = bfp[(ks * 2 + 0) * 64 + lane];
            const char* p0 = (const char*)xs + dh * (ROWB * 2) + off6[dw * 2 + cbi];
            const bfrag_t pf0 = *(const bfrag_t*)p0;
            const bfrag_t pf1 = *(const bfrag_t*)(p0 + ROWB * 2);
            acc0 = MFB(ahi, pf0, acc0);
            acc1 = MFB(ahi, pf1, acc1);
            if constexpr (!BB) {
                const bfrag_t alo = bfp[(ks * 2 + 1) * 64 + lane];
                acc0 = MFB(alo, pf0, acc0);
                acc1 = MFB(alo, pf1, acc1);
            }
        }
    }

    // ---- kh-reduce via LDS overlay, then write tmp (tiny, coalesced).
    __syncthreads();
    float (*tmp2)[HB][Rr][66] = (float (*)[HB][Rr][66])xs;  // [2][2][16][66]

#pragma unroll
    for (int reg = 0; reg < 4; ++reg) {
        tmp2[kh][0][g * 4 + reg][t * 16 + col] = acc0[reg];
        tmp2[kh][1][g * 4 + reg][t * 16 + col] = acc1[reg];
    }
    __syncthreads();

    // wave wv -> (row = wv>>2, r-group = (wv&3)*4); lane = px (coalesced)
    {
        const int row  = wv >> 2;
        const int rgrp = (wv & 3) * 4;
        if (lane < Ww) {
#pragma unroll
            for (int rr = 0; rr < 4; ++rr) {
                const int r = rgrp + rr;
                const float v = tmp2[0][row][r][lane] + tmp2[1][row][r][lane];
                tmpo[(size_t)(b * Rr + r) * Ll + (size_t)((h0 + row) * Ww) + lane] = v;
            }
        }
    }
}

__global__ __launch_bounds__(512, 4) void k1_tmp(
    const void* __restrict__ x,
    const void* __restrict__ Bm,
    const unsigned short* __restrict__ Bfrag,
    float* __restrict__ tmpo)
{
    __shared__ __align__(16) unsigned short xs[4 * ROWB];   // 59392 B
    const bool xb = detect_bf16(x);
    const bool bb = detect_bf16(Bm);
    if (xb) { if (bb) k1_body<true , true >(x, Bfrag, tmpo, xs);
              else    k1_body<true , false>(x, Bfrag, tmpo, xs); }
    else    { if (bb) k1_body<false, true >(x, Bfrag, tmpo, xs);
              else    k1_body<false, false>(x, Bfrag, tmpo, xs); }
}

// ---- K2: out[b][o][l] = sum_r Afp[o][r] * tmp[b][r][l]. Pure streaming.
// grid 896 = 16 b x 8 o-chunks x 7 l-chunks; 448 thr; l = chunk*448 + tid
// (7*448 = 3136 exact, no guards). (b, oc) block-uniform -> A via s_load.
__global__ __launch_bounds__(448) void k2_expand(
    const float* __restrict__ tmp,
    const float* __restrict__ Afp,
    float* __restrict__ out)
{
    const int gid   = blockIdx.x;         // 0..895
    const int chunk = gid % 7;
    const int oc    = (gid / 7) & 7;
    const int b     = gid / 56;
    const int l     = chunk * 448 + threadIdx.x;

    const float* tb = tmp + (size_t)(b * Rr) * Ll + l;
    float t[Rr];
#pragma unroll
    for (int r = 0; r < Rr; ++r) t[r] = tb[(size_t)r * Ll];   // coalesced, L3

    const size_t obase = (size_t)(b * Oo) * Ll + (size_t)l;
    const int o0 = oc * 32;
#pragma unroll 4
    for (int j = 0; j < 32; ++j) {
        const int o = o0 + j;
        const float* Ao = Afp + (size_t)o * Rr;   // uniform -> s_load
        float s = 0.f;
#pragma unroll
        for (int r = 0; r < Rr; ++r) s += Ao[r] * t[r];
        __builtin_nontemporal_store(s, &out[obase + (size_t)o * Ll]);
    }
}

// ---- fallback (ws too small): slow but correct, no workspace.
__global__ __launch_bounds__(256) void fused_fallback(
    const void* __restrict__ x, const void* __restrict__ A,
    const void* __restrict__ Bm, float* __restrict__ out)
{
    const bool xb = detect_bf16(x);
    const bool ab = detect_bf16(A);
    const bool bb = detect_bf16(Bm);
    const int gid = blockIdx.x * 256 + threadIdx.x;
    const int b = gid / Ll;
    const int l = gid - b * Ll;
    const int h = l / Ww, w = l - h * Ww;
    float acc[Rr];
#pragma unroll
    for (int r = 0; r < Rr; ++r) acc[r] = 0.f;
    const size_t xbase = (size_t)b * Cc * Ll;
    for (int c = 0; c < Cc; ++c) {
        const size_t xc = xbase + (size_t)c * Ll;
        float xv[9];
#pragma unroll
        for (int dh = 0; dh < 3; ++dh) {
            const int hh = h + dh - 1;
            const bool hok = (hh >= 0) & (hh < Hh);
#pragma unroll
            for (int dw = 0; dw < 3; ++dw) {
                const int ww = w + dw - 1;
                const bool ok = hok & (ww >= 0) & (ww < Ww);
                const size_t idx = xc + (size_t)(hh * Ww + ww);
                xv[dh*3+dw] = ok ? (xb ? bf16_bits(((const unsigned short*)x)[idx])
                                       : ((const float*)x)[idx]) : 0.f;
            }
        }
#pragma unroll
        for (int r = 0; r < Rr; ++r) {
            const size_t bo = (size_t)r * KF + (size_t)c * 9;
            float s = acc[r];
#pragma unroll
            for (int i = 0; i < 9; ++i)
                s += (bb ? bf16_bits(((const unsigned short*)Bm)[bo+i])
                         : ((const float*)Bm)[bo+i]) * xv[i];
            acc[r] = s;
        }
    }
    const size_t obase = (size_t)b * Oo * Ll + (size_t)l;
    for (int o = 0; o < Oo; ++o) {
        float s = 0.f;
#pragma unroll
        for (int r = 0; r < Rr; ++r)
            s += (ab ? bf16_bits(((const unsigned short*)A)[o*Rr+r])
                     : ((const float*)A)[o*Rr+r]) * acc[r];
        out[obase + (size_t)o * Ll] = s;
    }
}

extern "C" void kernel_launch(void* const* d_in, const int* in_sizes, int n_in,
                              void* d_out, int out_size, void* d_ws, size_t ws_size,
                              hipStream_t stream) {
    const void* x  = d_in[0];
    const void* A  = d_in[1];
    const void* Bm = d_in[2];
    for (int i = 0; i < n_in && i < 3; ++i) {
        const int s = in_sizes[i];
        if      (s == Bn * Cc * Ll) x  = d_in[i];
        else if (s == Oo * Rr)      A  = d_in[i];
        else if (s == Rr * KF)      Bm = d_in[i];
    }
    float* out = (float*)d_out;

    const size_t frag_bytes = (size_t)(NKS * 2 * 512) * 2;           // 73728
    const size_t afp_bytes  = (size_t)(Oo * Rr) * 4;                 // 16384
    const size_t tmp_bytes  = (size_t)Bn * Rr * Ll * 4;              // 3211264
    const size_t need       = frag_bytes + afp_bytes + tmp_bytes;    // ~3.3 MB

    if (ws_size >= need) {
        unsigned short* Bfrag = (unsigned short*)d_ws;
        float* Afp  = (float*)((char*)d_ws + frag_bytes);
        float* tmpo = (float*)((char*)d_ws + frag_bytes + afp_bytes);
        prep_frag<<<dim3(72), 256, 0, stream>>>(A, Bm, Bfrag, Afp);
        k1_tmp   <<<dim3(448), 512, 0, stream>>>(x, Bm, Bfrag, tmpo);
        k2_expand<<<dim3(896), 448, 0, stream>>>(tmpo, Afp, out);
    } else {
        fused_fallback<<<dim3((Bn * Ll) / 256), 256, 0, stream>>>(x, A, Bm, out);
    }
}

// Round 16
// 103.017 us; speedup vs baseline: 1.0331x; 1.0331x over previous
//
#include <hip/hip_runtime.h>
#include <hip/hip_bf16.h>

// LoRA-factored 3x3 conv. out fp32. Input dtypes runtime-detected.
// x: [16,128,56,56], A: [256,16], B: [16,1152] -> out: [16,256,56,56]
// R20 = R17 (best: 103.5us total, PASSED) + two verified micro-levers:
//  (1) XCD-aware block map (lifted from R19's PASSED K1): XCD k owns
//      batches {2k,2k+1}; consecutive same-XCD blocks = consecutive hb ->
//      the 2 staged rows shared between hb-neighbors hit the same 4MB L2.
//      Targets measured 1.6x x over-fetch (FETCH 29 vs 16MB ideal).
//  (2) nt-stores in epilogue (R10: harmless): 51MB write stream stops
//      occupying L2 the x rows need.
// Experiment ledger (all vs ~31us fused): skip-lo null (R17), 2x TLP null
// (R18), finer blocks - (R16), kernel split - (R19), LDS-B - (R7),
// HB=4 spills (R8/R9). Structure is at its phase-latency floor.
// Verified carried bytes: 512thr 8 waves = 4 px-tiles x 2 K-halves,
// swizzled [px][c] LDS (slot^(px&7), 256B pitch), batched b128 staging,
// b128 read addressing, Bfrag hi/lo frag order + skip-lo when B bf16,
// C layout col=lane&15,row=(lane>>4)*4+reg, kh-reduce overlay, fp32
// stage-2, detect (R3).

#define Bn 16
#define Cc 128
#define Hh 56
#define Ww 56
#define Ll (Hh * Ww)      // 3136
#define Rr 16
#define Oo 256
#define KF (Cc * 9)       // 1152
#define NKS 36            // K-steps: 1152/32
#define W2 58             // padded px range
#define RPITCH 128        // u16 per pixel in LDS (=256B, no pad)
#define ROWB (W2 * RPITCH) // 7424 u16 per staged row
#define HB 2              // output rows per block

typedef __attribute__((ext_vector_type(8))) short bfrag_t;  // 8 bf16 (16B)
typedef __attribute__((ext_vector_type(4))) float f32x4;    // C frag

__device__ __forceinline__ float bf16_bits(unsigned short u) {
    return __uint_as_float(((unsigned)u) << 16);
}

__device__ __forceinline__ unsigned short bf16_rne(float f) {
    const unsigned u = __float_as_uint(f);
    const unsigned r = u + 0x7FFFu + ((u >> 16) & 1u);
    return (unsigned short)(r >> 16);
}

// bf16-packed detect (proven R3).
__device__ __forceinline__ bool detect_bf16(const void* __restrict__ p) {
    const unsigned* w = (const unsigned*)p;
    int c = 0;
#pragma unroll
    for (int i = 0; i < 32; ++i) {
        const unsigned e = (w[i] >> 7) & 0xFFu;
        c += (e >= 96u && e <= 144u) ? 1 : 0;
    }
    return c >= 20;
}

// ---- prep: Bfrag[kstep][hi/lo][lane][8e] bf16 (frag order, tap-major K),
//      Afp[o][r] fp32. (Unchanged R11-R19 - harness-verified.)
__global__ __launch_bounds__(256) void prep_frag(
    const void* __restrict__ A, const void* __restrict__ Bm,
    unsigned short* __restrict__ Bfrag, float* __restrict__ Afp)
{
    const bool ab = detect_bf16(A);
    const bool bb = detect_bf16(Bm);
    const int i = blockIdx.x * 256 + threadIdx.x;
    if (i < NKS * 512) {
        const int kstep = i >> 9, rem = i & 511;
        const int l = rem >> 3, e = rem & 7;
        const int r = l & 15, g = l >> 4;
        const int kp = kstep * 32 + g * 8 + e;   // tap-major k'
        const int tap = kp >> 7, c = kp & 127;
        const int k = c * 9 + tap;               // torch Unfold order (c,kh,kw)
        const float v = bb ? bf16_bits(((const unsigned short*)Bm)[r * KF + k])
                           : ((const float*)Bm)[r * KF + k];
        const unsigned short hi = bf16_rne(v);
        const float lov = v - bf16_bits(hi);
        Bfrag[(kstep * 2 + 0) * 512 + rem] = hi;
        Bfrag[(kstep * 2 + 1) * 512 + rem] = bf16_rne(lov);
    }
    if (i < Oo * Rr) {
        Afp[i] = ab ? bf16_bits(((const unsigned short*)A)[i])
                    : ((const float*)A)[i];
    }
}

#define MFB(A, B, C) __builtin_amdgcn_mfma_f32_16x16x32_bf16((A), (B), (C), 0, 0, 0)

// ---- fused main: one block = (b, rows h0,h0+1). 8 waves = 4 px-tiles x 2 K-halves.
// BB = B-input-is-bf16: lo correction identically zero -> skip alo loads+MFMAs.
template<bool XB, bool BB>
__device__ __forceinline__ void fused_body(
    const void* __restrict__ x,
    const unsigned short* __restrict__ Bfrag,
    const float* __restrict__ Afp,
    float* __restrict__ out,
    unsigned short* __restrict__ xs)      // [4*ROWB] u16, 59392 B
{
    const int tid  = threadIdx.x;
    const int lane = tid & 63;
    const int wv   = __builtin_amdgcn_readfirstlane(tid >> 6);  // wave 0..7
    const int t    = wv & 3;              // px-tile 0..3
    const int kh   = wv >> 2;             // K-half 0..1 (cb pair)

    // XCD-aware map (R19 K1, PASSED): XCD = lin&7 owns batches {2k,2k+1};
    // consecutive same-XCD blocks = consecutive hb -> shared staged rows
    // (2 of 4 per neighbor pair) are same-L2 hits.
    const int lin  = blockIdx.x;          // 0..447
    const int xcd  = lin & 7;
    const int j    = lin >> 3;            // 0..55
    const int boff = (j >= 28) ? 1 : 0;
    const int hb   = j - 28 * boff;
    const int b    = xcd * 2 + boff;
    const int h0   = hb * HB;

    // ---- stage 4 x-rows (h0-1 .. h0+2) into swizzled LDS [px][c].
    // Per (row, cslot) task: lane l (w=l, px=l+1) loads 8 consecutive
    // channels (8 coalesced u16 row-loads) -> ONE ds_write_b128 at
    // byte = px*256 + ((cslot ^ (px&7))<<4). 64 tasks / 8 waves.
    {
        const int l   = lane;
        const bool lok = (l < Ww);
#pragma unroll
        for (int rr = 0; rr < HB + 2; ++rr) {
            const int hh = h0 - 1 + rr;
            unsigned short* xr = xs + rr * ROWB;
            if (hh >= 0 && hh < Hh) {
                if (lok) {
                    const unsigned gb = (unsigned)(b * Cc * Ll + hh * Ww + l);
#pragma unroll
                    for (int it = 0; it < 2; ++it) {
                        const int cs_ = it * 8 + wv;     // cslot 0..15
                        const int c0  = cs_ * 8;
                        bfrag_t v;
#pragma unroll
                        for (int jj = 0; jj < 8; ++jj) {
                            if constexpr (XB) {
                                v[jj] = (short)((const unsigned short*)x)[
                                    gb + (unsigned)((c0 + jj) * Ll)];
                            } else {
                                v[jj] = (short)bf16_rne(((const float*)x)[
                                    gb + (unsigned)((c0 + jj) * Ll)]);
                            }
                        }
                        const int sp = cs_ ^ ((l + 1) & 7);
                        *(bfrag_t*)((char*)xr + (l + 1) * 256 + sp * 16) = v;
                    }
                }
            } else {
                // zero whole row: 3712 dwords, 512 threads
                unsigned* xw = (unsigned*)xr;
#pragma unroll
                for (int it = 0; it < 7; ++it) xw[it * 512 + tid] = 0u;
                if (tid < 3712 - 7 * 512) xw[7 * 512 + tid] = 0u;
            }
        }
        // zero px borders (px=0, px=57) on all rows (covers any swizzle)
        if (tid < 128) {
#pragma unroll
            for (int rr = 0; rr < HB + 2; ++rr) {
                xs[rr * ROWB + tid] = 0;
                xs[rr * ROWB + 57 * RPITCH + tid] = 0;
            }
        }
    }
    __syncthreads();

    // ---- stage 1: MFMA over this wave's K-half (cb in {2kh, 2kh+1}).
    const int col = lane & 15;
    const int g   = lane >> 4;
    const int px  = t * 16 + col;              // output pixel w (valid < 56)
    const int pxc = px < Ww ? px : Ww - 1;     // clamp lanes' px 56..63

    // 6 per-lane swizzled LDS byte offsets: [dw][cbi]
    unsigned off6[6];
#pragma unroll
    for (int dwv = 0; dwv < 3; ++dwv)
#pragma unroll
        for (int cbi = 0; cbi < 2; ++cbi) {
            const int cb = kh * 2 + cbi;
            const int p2 = pxc + dwv;          // window px-index w..w+2
            off6[dwv * 2 + cbi] = (unsigned)(p2 * 256 +
                (((cb * 4 + g) ^ (p2 & 7)) << 4));
        }

    f32x4 acc0 = {0.f, 0.f, 0.f, 0.f};
    f32x4 acc1 = {0.f, 0.f, 0.f, 0.f};
    const bfrag_t* __restrict__ bfp = (const bfrag_t*)Bfrag;

#pragma unroll
    for (int tap = 0; tap < 9; ++tap) {
        const int dh = tap / 3, dw = tap - dh * 3;
#pragma unroll
        for (int cbi = 0; cbi < 2; ++cbi) {
            const int cb = kh * 2 + cbi;
            const int ks = tap * 4 + cb;
            const bfrag_t ahi = bfp[(ks * 2 + 0) * 64 + lane];  // 16B/lane L2
            const char* p0 = (const char*)xs + dh * (ROWB * 2) + off6[dw * 2 + cbi];
            const bfrag_t pf0 = *(const bfrag_t*)p0;            // 16B aligned
            const bfrag_t pf1 = *(const bfrag_t*)(p0 + ROWB * 2);
            acc0 = MFB(ahi, pf0, acc0);
            acc1 = MFB(ahi, pf1, acc1);
            if constexpr (!BB) {
                // fp32 B: apply lo-correction fragments too
                const bfrag_t alo = bfp[(ks * 2 + 1) * 64 + lane];
                acc0 = MFB(alo, pf0, acc0);
                acc1 = MFB(alo, pf1, acc1);
            }
        }
    }

    // ---- LDS reuse: overlay partial-C on xs; reduce K-halves; stage 2.
    __syncthreads();
    float (*tmp2)[HB][Rr][66] = (float (*)[HB][Rr][66])xs;  // [2][2][16][66]

    // C layout: col=lane&15 (px), row=(lane>>4)*4+reg  [R11-R19 verified]
#pragma unroll
    for (int reg = 0; reg < 4; ++reg) {
        tmp2[kh][0][g * 4 + reg][t * 16 + col] = acc0[reg];
        tmp2[kh][1][g * 4 + reg][t * 16 + col] = acc1[reg];
    }
    __syncthreads();

    float tv0[Rr], tv1[Rr];
#pragma unroll
    for (int r = 0; r < Rr; ++r) {
        tv0[r] = tmp2[0][0][r][lane] + tmp2[1][0][r][lane];
        tv1[r] = tmp2[0][1][r][lane] + tmp2[1][1][r][lane];
    }

    const bool wok = (lane < Ww);
    const size_t obase = (size_t)b * Oo * Ll + (size_t)(h0 * Ww) + (size_t)lane;
#pragma unroll 4
    for (int j2 = 0; j2 < 32; ++j2) {
        const int o = wv * 32 + j2;                // 8 waves x 32 = 256
        const float* Ao = Afp + (size_t)o * Rr;    // uniform -> s_load
        float s0 = 0.f, s1 = 0.f;
#pragma unroll
        for (int r = 0; r < Rr; ++r) {
            const float av = Ao[r];
            s0 += av * tv0[r];
            s1 += av * tv1[r];
        }
        if (wok) {
            // nt: write-once stream; keep it out of the L2 that x rows use
            __builtin_nontemporal_store(s0, &out[obase + (size_t)o * Ll]);
            __builtin_nontemporal_store(s1, &out[obase + (size_t)o * Ll + Ww]);
        }
    }
}

__global__ __launch_bounds__(512, 4) void fused_ks(
    const void* __restrict__ x,
    const void* __restrict__ Bm,
    const unsigned short* __restrict__ Bfrag,
    const float* __restrict__ Afp,
    float* __restrict__ out)
{
    __shared__ __align__(16) unsigned short xs[4 * ROWB];   // 59392 B
    const bool xb = detect_bf16(x);
    const bool bb = detect_bf16(Bm);
    if (xb) { if (bb) fused_body<true , true >(x, Bfrag, Afp, out, xs);
              else    fused_body<true , false>(x, Bfrag, Afp, out, xs); }
    else    { if (bb) fused_body<false, true >(x, Bfrag, Afp, out, xs);
              else    fused_body<false, false>(x, Bfrag, Afp, out, xs); }
}

// ---- fallback (ws too small): slow but correct, no workspace.
__global__ __launch_bounds__(256) void fused_fallback(
    const void* __restrict__ x, const void* __restrict__ A,
    const void* __restrict__ Bm, float* __restrict__ out)
{
    const bool xb = detect_bf16(x);
    const bool ab = detect_bf16(A);
    const bool bb = detect_bf16(Bm);
    const int gid = blockIdx.x * 256 + threadIdx.x;
    const int b = gid / Ll;
    const int l = gid - b * Ll;
    const int h = l / Ww, w = l - h * Ww;
    float acc[Rr];
#pragma unroll
    for (int r = 0; r < Rr; ++r) acc[r] = 0.f;
    const size_t xbase = (size_t)b * Cc * Ll;
    for (int c = 0; c < Cc; ++c) {
        const size_t xc = xbase + (size_t)c * Ll;
        float xv[9];
#pragma unroll
        for (int dh = 0; dh < 3; ++dh) {
            const int hh = h + dh - 1;
            const bool hok = (hh >= 0) & (hh < Hh);
#pragma unroll
            for (int dw = 0; dw < 3; ++dw) {
                const int ww = w + dw - 1;
                const bool ok = hok & (ww >= 0) & (ww < Ww);
                const size_t idx = xc + (size_t)(hh * Ww + ww);
                xv[dh*3+dw] = ok ? (xb ? bf16_bits(((const unsigned short*)x)[idx])
                                       : ((const float*)x)[idx]) : 0.f;
            }
        }
#pragma unroll
        for (int r = 0; r < Rr; ++r) {
            const size_t bo = (size_t)r * KF + (size_t)c * 9;
            float s = acc[r];
#pragma unroll
            for (int i = 0; i < 9; ++i)
                s += (bb ? bf16_bits(((const unsigned short*)Bm)[bo+i])
                         : ((const float*)Bm)[bo+i]) * xv[i];
            acc[r] = s;
        }
    }
    const size_t obase = (size_t)b * Oo * Ll + (size_t)l;
    for (int o = 0; o < Oo; ++o) {
        float s = 0.f;
#pragma unroll
        for (int r = 0; r < Rr; ++r)
            s += (ab ? bf16_bits(((const unsigned short*)A)[o*Rr+r])
                     : ((const float*)A)[o*Rr+r]) * acc[r];
        out[obase + (size_t)o * Ll] = s;
    }
}

extern "C" void kernel_launch(void* const* d_in, const int* in_sizes, int n_in,
                              void* d_out, int out_size, void* d_ws, size_t ws_size,
                              hipStream_t stream) {
    const void* x  = d_in[0];
    const void* A  = d_in[1];
    const void* Bm = d_in[2];
    for (int i = 0; i < n_in && i < 3; ++i) {
        const int s = in_sizes[i];
        if      (s == Bn * Cc * Ll) x  = d_in[i];
        else if (s == Oo * Rr)      A  = d_in[i];
        else if (s == Rr * KF)      Bm = d_in[i];
    }
    float* out = (float*)d_out;

    const size_t frag_bytes = (size_t)(NKS * 2 * 512) * 2;          // 73728
    const size_t afp_bytes  = (size_t)(Oo * Rr) * 4;                // 16384
    const size_t need       = frag_bytes + afp_bytes;               // 90112

    if (ws_size >= need) {
        unsigned short* Bfrag = (unsigned short*)d_ws;
        float* Afp = (float*)((char*)d_ws + frag_bytes);
        prep_frag<<<dim3(72), 256, 0, stream>>>(A, Bm, Bfrag, Afp);
        fused_ks<<<dim3(448), 512, 0, stream>>>(x, Bm, Bfrag, Afp, out);
    } else {
        fused_fallback<<<dim3((Bn * Ll) / 256), 256, 0, stream>>>(x, A, Bm, out);
    }
}